// Round 7
// baseline (1145.167 us; speedup 1.0000x reference)
//
#include <hip/hip_runtime.h>
#include <math.h>

#define NB 4
#define NC 20
#define NH 480
#define NW 640
#define NPIX (NH*NW)      // 307200
#define NM 480
#define NVR 100
#define NNZ 80
#define ZLO 13
#define ZHI 25
#define NZB 12
#define NBINS 101         // y0 bucket 0..100 (100 = dead)
#define SREC_CAP 786432   // band-record capacity (est ~370K)
#define NB2D 40400        // 4 * 101 * 100 (y0,x0) bins

// workspace offsets
#define WS_HIST     0
#define WS_STARTS   2048
#define WS_CURS     4096
#define WS_PARAMS   6144
#define WS_H2D      8192                              // 40400 ints
#define WS_S2D      172032                            // 40401 ints
#define WS_C2D      335872                            // 40400 ints
#define WS_RECS     499712                            // 1,228,800 * 16B
#define WS_PROJ     (WS_RECS + 19660800)              // 20,160,512
#define WS_SGEOM    (WS_PROJ + 3200000)               // 23,360,512
#define WS_SEMT     (WS_SGEOM + (size_t)SREC_CAP*16)  // 35,943,424
#define WS_FAST_END (WS_SEMT + (size_t)NB*NPIX*16*4)  // 114,586,624 (ws >= 118MB proven)

// exact replication of the reference f32 op chains
__device__ __forceinline__ float p1_chain(float d) {
  float xy1 = d / 5.0f;
  xy1 = (xy1 - 50.0f) / 100.0f * 2.0f;
  return xy1 * 50.0f + 50.0f;
}
__device__ __forceinline__ void p02_chain(float d, int row, int col, float foc,
                                          float& p0, float& p2) {
  float X = ((float)col - 319.5f) * d / foc;
  float Z = ((float)(479 - row) - 239.5f) * d / foc;
  float xy0 = (X + 250.0f) / 5.0f;
  xy0 = (xy0 - 50.0f) / 100.0f * 2.0f;
  float zz = (Z + 88.0f) / 5.0f;
  zz = (zz - 32.0f) / 80.0f * 2.0f;
  p0 = xy0 * 50.0f + 50.0f;
  p2 = zz * 40.0f + 40.0f;
}
__device__ __forceinline__ bool band_ok(float p0, float p2) {
  return (p0 > 0.0f) && (p0 < 100.0f) &&
         (p2 > (float)(ZLO - 1)) && (p2 < (float)ZHI);
}

// ---------------- pose + affine params ----------------
__global__ __launch_bounds__(64) void pose_kernel(
    const float* __restrict__ pose_obs, const float* __restrict__ poses_last,
    float* __restrict__ out_poses, float* __restrict__ params)
{
  int b = threadIdx.x;
  if (b >= NB) return;
  const float R2D = 57.29577951308232f;
  float plx = poses_last[b*3+0], ply = poses_last[b*3+1], plo = poses_last[b*3+2];
  float dx = pose_obs[b*3+0], dy = pose_obs[b*3+1], dth = pose_obs[b*3+2];
  float r = plo / R2D;
  float sr = sinf(r), cr = cosf(r);
  float yy = ply + dx*sr + dy*cr;
  float xx = plx + dx*cr - dy*sr;
  float oo = plo + dth*R2D;
  oo = fmodf(oo - 180.0f, 360.0f) + 180.0f;
  oo = fmodf(oo + 180.0f, 360.0f) - 180.0f;
  out_poses[b*3+0] = xx;
  out_poses[b*3+1] = yy;
  out_poses[b*3+2] = oo;
  float tx = -((xx*100.0f/5.0f) - 240.0f) / 240.0f;
  float ty = -((yy*100.0f/5.0f) - 240.0f) / 240.0f;
  float th = ((90.0f - oo) * 3.14159274101257324f) / 180.0f;
  params[b*4+0] = cosf(th);
  params[b*4+1] = sinf(th);
  params[b*4+2] = tx;
  params[b*4+3] = ty;
}

// ---------------- sem transpose: semT[b][pid][16] ----------------
__global__ __launch_bounds__(256) void semt_kernel(
    const float* __restrict__ obs, float* __restrict__ semT)
{
  int b = blockIdx.x / 1200, blk = blockIdx.x % 1200;
  int p = blk*256 + threadIdx.x;
  const float* src = obs + ((size_t)b*NC + 4)*NPIX + p;
  float v[16];
  #pragma unroll
  for (int s = 0; s < 16; ++s) v[s] = src[(size_t)s*NPIX];
  float4* dst = (float4*)(semT + ((size_t)b*NPIX + p)*16);
  dst[0] = make_float4(v[0],  v[1],  v[2],  v[3]);
  dst[1] = make_float4(v[4],  v[5],  v[6],  v[7]);
  dst[2] = make_float4(v[8],  v[9],  v[10], v[11]);
  dst[3] = make_float4(v[12], v[13], v[14], v[15]);
}

// ---------------- histogram: y-buckets (LDS) + (y,x) 2D bins (global atomics) ----------------
__global__ __launch_bounds__(256) void hist_kernel(
    const float* __restrict__ obs, int* __restrict__ hist, int* __restrict__ h2d,
    float foc, int do2d)
{
  int b = blockIdx.x / 300, blk = blockIdx.x % 300;
  __shared__ int lh[NBINS];
  for (int i = threadIdx.x; i < NBINS; i += 256) lh[i] = 0;
  __syncthreads();
  int pix0 = (blk*256 + threadIdx.x)*4;
  int row = pix0 / NW;
  int c0 = pix0 - row*NW;
  const float4* dp = (const float4*)(obs + ((size_t)b*NC + 3)*NPIX);
  float4 dv = dp[blk*256 + threadIdx.x];
  float dvv[4] = {dv.x, dv.y, dv.z, dv.w};
  #pragma unroll
  for (int k = 0; k < 4; ++k) {
    float p1 = p1_chain(dvv[k]);
    int y0 = (int)floorf(p1);
    y0 = min(max(y0, 0), 100);
    atomicAdd(&lh[y0], 1);
    float p0, p2;
    p02_chain(dvv[k], row, c0 + k, foc, p0, p2);
    if (do2d && band_ok(p0, p2)) {
      int x0 = (int)floorf(p0);            // band -> 0..99
      atomicAdd(&h2d[(b*NBINS + y0)*100 + x0], 1);
    }
  }
  __syncthreads();
  for (int i = threadIdx.x; i < NBINS; i += 256)
    if (lh[i]) atomicAdd(&hist[b*NBINS + i], lh[i]);
}

// ---------------- exclusive scan of y-bins ----------------
__global__ __launch_bounds__(512) void scan_kernel(
    const int* __restrict__ hist, int* __restrict__ starts, int* __restrict__ cursors)
{
  __shared__ int lh[NB*NBINS];
  __shared__ int ls[NB*NBINS + 1];
  for (int i = threadIdx.x; i < NB*NBINS; i += 512) lh[i] = hist[i];
  __syncthreads();
  if (threadIdx.x == 0) {
    int s = 0;
    for (int i = 0; i < NB*NBINS; ++i) { ls[i] = s; s += lh[i]; }
    ls[NB*NBINS] = s;
  }
  __syncthreads();
  for (int i = threadIdx.x; i < NB*NBINS + 1; i += 512) {
    starts[i] = ls[i];
    if (i < NB*NBINS) cursors[i] = ls[i];
  }
}

// ---------------- exclusive scan of 40400 2D bins ----------------
__global__ __launch_bounds__(512) void scan2d_kernel(
    const int* __restrict__ h2d, int* __restrict__ s2d, int* __restrict__ c2d)
{
  __shared__ int part[512];
  __shared__ int base[512];
  const int CH = 79;                       // 512*79 >= 40400
  int t = threadIdx.x;
  int s = 0;
  for (int i = 0; i < CH; ++i) {
    int idx = t*CH + i;
    if (idx < NB2D) s += h2d[idx];
  }
  part[t] = s;
  __syncthreads();
  if (t == 0) {
    int run = 0;
    for (int k = 0; k < 512; ++k) { base[k] = run; run += part[k]; }
    s2d[NB2D] = run;
  }
  __syncthreads();
  int run = base[t];
  for (int i = 0; i < CH; ++i) {
    int idx = t*CH + i;
    if (idx < NB2D) { s2d[idx] = run; c2d[idx] = run; run += h2d[idx]; }
  }
}

// ---------------- scatter pixel records into buckets ----------------
__global__ __launch_bounds__(256) void scatter_kernel(
    const float* __restrict__ obs, int* __restrict__ cursors, int* __restrict__ c2d,
    float4* __restrict__ recs, float4* __restrict__ sgeom,
    float foc, int do_band)
{
  int b = blockIdx.x / 300, blk = blockIdx.x % 300;
  __shared__ int lh[NBINS], lbase[NBINS], loff[NBINS];
  for (int i = threadIdx.x; i < NBINS; i += 256) { lh[i] = 0; loff[i] = 0; }
  __syncthreads();
  int pix0 = (blk*256 + threadIdx.x)*4;
  int row = pix0 / NW;
  int c0 = pix0 - row*NW;   // 4-pixel group never crosses a row (640 % 4 == 0)
  const float4* dp = (const float4*)(obs + ((size_t)b*NC + 3)*NPIX);
  float4 dv = dp[blk*256 + threadIdx.x];
  float dvv[4] = {dv.x, dv.y, dv.z, dv.w};
  float rp0[4], rp1[4], rp2[4]; int rbin[4];
  #pragma unroll
  for (int k = 0; k < 4; ++k) {
    float p1 = p1_chain(dvv[k]);
    float p0, p2;
    p02_chain(dvv[k], row, c0 + k, foc, p0, p2);
    rp0[k] = p0; rp1[k] = p1; rp2[k] = p2;
    int y0 = (int)floorf(p1); y0 = min(max(y0, 0), 100);
    rbin[k] = y0;
    atomicAdd(&lh[y0], 1);
  }
  __syncthreads();
  for (int i = threadIdx.x; i < NBINS; i += 256)
    if (lh[i] > 0) lbase[i] = atomicAdd(&cursors[b*NBINS + i], lh[i]);
  __syncthreads();
  #pragma unroll
  for (int k = 0; k < 4; ++k) {
    int idx = atomicAdd(&loff[rbin[k]], 1);
    recs[lbase[rbin[k]] + idx] =
        make_float4(rp0[k], rp1[k], rp2[k], __int_as_float(pix0 + k));
    if (do_band && band_ok(rp0[k], rp2[k])) {
      int x0 = (int)floorf(rp0[k]);
      int bin = (b*NBINS + rbin[k])*100 + x0;
      int j = atomicAdd(&c2d[bin], 1);
      if (j < SREC_CAP)
        sgeom[j] = make_float4(rp0[k], rp1[k], rp2[k], __int_as_float(pix0 + k));
    }
  }
}

// ---------------- ch0 slab, unroll-4 prefetch (unchanged) ----------------
__global__ __launch_bounds__(256) void slab0f_kernel(
    const float4* __restrict__ recs, const int* __restrict__ starts,
    float* __restrict__ proj, float* __restrict__ out_fp)
{
  int b = blockIdx.x / NVR, Y = blockIdx.x % NVR;
  __shared__ float g[NVR*81];
  for (int i = threadIdx.x; i < NVR*81; i += 256) g[i] = 0.0f;
  __syncthreads();
  if (Y > 0) {
    int lo = starts[b*NBINS + Y - 1];
    int hi = starts[b*NBINS + Y + 1];
    float Yf = (float)Y;
    for (int i = lo + threadIdx.x; i < hi; i += 1024) {
      float4 rr[4];
      #pragma unroll
      for (int k = 0; k < 4; ++k) {
        int j = i + k*256;
        rr[k] = (j < hi) ? recs[j] : make_float4(0.0f, -1.0e9f, 0.0f, 0.0f);
      }
      #pragma unroll
      for (int k = 0; k < 4; ++k) {
        float4 r = rr[k];
        float wy = 1.0f - fabsf(r.y - Yf);
        if (wy <= 0.0f) continue;
        float p0 = r.x, p2 = r.z;
        float fl0 = floorf(p0), fl2 = floorf(p2);
        #pragma unroll
        for (int xo = 0; xo < 2; ++xo) {
          float px = fl0 + (float)xo;
          if (!(px > 0.0f && px < 100.0f)) continue;
          float wxy = (1.0f - fabsf(p0 - px)) * wy;
          if (wxy <= 0.0f) continue;
          int ix = (int)px;
          #pragma unroll
          for (int zo = 0; zo < 2; ++zo) {
            float pz = fl2 + (float)zo;
            if (!(pz > 0.0f && pz < 80.0f)) continue;
            float w = wxy * (1.0f - fabsf(p2 - pz));
            if (w > 0.0f) atomicAdd(&g[ix*81 + (int)pz], w);
          }
        }
      }
    }
  }
  __syncthreads();
  if (threadIdx.x < NVR) {
    int x = threadIdx.x;
    float s_all = 0.0f, s_ag = 0.0f;
    for (int z = 0; z < NNZ; ++z) {
      float v = rintf(g[x*81 + z]);
      s_all += v;
      if (z >= ZLO && z < ZHI) s_ag += v;
    }
    float fp_map = fminf(fmaxf(s_ag, 0.0f), 1.0f);
    float fp_exp = fminf(fmaxf(s_all, 0.0f), 1.0f);
    size_t pb = (((size_t)b*NC + 0)*NVR + Y)*NVR + x;
    proj[pb] = fp_map;
    proj[pb + NVR*NVR] = fp_exp;
    proj[pb + 2*NVR*NVR] = 0.0f;
    proj[pb + 3*NVR*NVR] = 0.0f;
    out_fp[(size_t)b*NVR*NVR + Y*NVR + x] = fp_map;
  }
}

// ---------------- sem slab: OWNER-COMPUTES GATHER, no atomics, no LDS ----------------
// block = (b,Y), 512 threads = 8 waves; wave w owns x columns [13w, 13w+13).
// All 64 lanes of a wave process the same record (broadcast); lane l owns
// (s = l&15, z cells zq*3..zq*3+2 where zq = l>>4) -> 3 register accumulators.
__global__ __launch_bounds__(512) void slab1g_kernel(
    const float* __restrict__ semT, const float4* __restrict__ sgeom,
    const int* __restrict__ s2d, float* __restrict__ proj)
{
  int b = blockIdx.x / NVR, Y = blockIdx.x % NVR;
  int wave = threadIdx.x >> 6;
  int lane = threadIdx.x & 63;
  int s = lane & 15;
  int zq = lane >> 4;
  float z0f = (float)(ZLO + zq*3);
  float Yf = (float)Y;
  const float* sT = semT + (size_t)b*NPIX*16 + s;

  int xbase = wave*13;
  #pragma unroll 1
  for (int xi = 0; xi < 13; ++xi) {
    int x = xbase + xi;
    if (x >= NVR) break;
    float acc0 = 0.0f, acc1 = 0.0f, acc2 = 0.0f;
    if (Y > 0 && x > 0) {
      float xf = (float)x;
      #pragma unroll 1
      for (int p = 0; p < 2; ++p) {
        int rowb = (b*NBINS + (Y - 1 + p))*100;
        int lo = s2d[rowb + x - 1];
        int hi = s2d[rowb + x + 1];
        #pragma unroll 1
        for (int i = lo; i < hi; i += 4) {
          int n = hi - i;
          float4 gm[4];
          #pragma unroll
          for (int k = 0; k < 4; ++k)
            gm[k] = (k < n) ? sgeom[i + k]
                            : make_float4(0.0f, -1.0e9f, 0.0f, __int_as_float(0));
          float sv[4];
          #pragma unroll
          for (int k = 0; k < 4; ++k) {
            int pid = __float_as_int(gm[k].w);
            sv[k] = sT[(size_t)pid*16];
          }
          #pragma unroll
          for (int k = 0; k < 4; ++k) {
            float wy = fmaxf(1.0f - fabsf(gm[k].y - Yf), 0.0f);
            float wx = fmaxf(1.0f - fabsf(gm[k].x - xf), 0.0f);
            float wxy = wx * wy;
            float p2 = gm[k].z;
            float ws0 = wxy * sv[k];
            acc0 += ws0 * fmaxf(1.0f - fabsf(p2 - z0f), 0.0f);
            acc1 += ws0 * fmaxf(1.0f - fabsf(p2 - (z0f + 1.0f)), 0.0f);
            acc2 += ws0 * fmaxf(1.0f - fabsf(p2 - (z0f + 2.0f)), 0.0f);
          }
        }
      }
    }
    float r = rintf(acc0) + rintf(acc1) + rintf(acc2);
    r += __shfl_xor(r, 16);
    r += __shfl_xor(r, 32);
    if (zq == 0)
      proj[(((size_t)b*NC + 4 + s)*NVR + Y)*NVR + x] =
          fminf(fmaxf(r / 5.0f, 0.0f), 1.0f);
  }
}

// ---------------- fallback sem slab (ws too small; R0-proven) ----------------
__global__ __launch_bounds__(256) void slab1_kernel(
    const float* __restrict__ obs, const float4* __restrict__ recs,
    const int* __restrict__ starts, float* __restrict__ proj)
{
  int half = blockIdx.x & 1;
  int t = blockIdx.x >> 1;
  int b = t / NVR, Y = t % NVR;
  __shared__ float g[NVR*NZB*8];
  for (int i = threadIdx.x; i < NVR*NZB*8; i += 256) g[i] = 0.0f;
  __syncthreads();
  if (Y > 0) {
    int lo = starts[b*NBINS + Y - 1];
    int hi = starts[b*NBINS + Y + 1];
    float Yf = (float)Y;
    const float* sbase = obs + ((size_t)b*NC + 4 + half*8)*NPIX;
    for (int i = lo + threadIdx.x; i < hi; i += 256) {
      float4 r = recs[i];
      float wy = 1.0f - fabsf(r.y - Yf);
      if (wy <= 0.0f) continue;
      float p2 = r.z;
      float fl2 = floorf(p2);
      float wz[2]; int iz[2]; bool any = false;
      #pragma unroll
      for (int zo = 0; zo < 2; ++zo) {
        float pz = fl2 + (float)zo;
        bool v = (pz >= (float)ZLO) && (pz < (float)ZHI);
        float w = v ? (1.0f - fabsf(p2 - pz)) : 0.0f;
        wz[zo] = w; iz[zo] = v ? ((int)pz - ZLO) : 0;
        any = any || (w > 0.0f);
      }
      if (!any) continue;
      float p0 = r.x;
      float fl0 = floorf(p0);
      int pid = __float_as_int(r.w);
      float sem[8];
      #pragma unroll
      for (int ss = 0; ss < 8; ++ss) sem[ss] = sbase[(size_t)ss*NPIX + pid];
      #pragma unroll
      for (int xo = 0; xo < 2; ++xo) {
        float px = fl0 + (float)xo;
        if (!(px > 0.0f && px < 100.0f)) continue;
        float wxy = (1.0f - fabsf(p0 - px)) * wy;
        if (wxy <= 0.0f) continue;
        int ix = (int)px;
        #pragma unroll
        for (int zo = 0; zo < 2; ++zo) {
          float w = wxy * wz[zo];
          if (w > 0.0f) {
            float* gb = &g[(ix*NZB + iz[zo])*8];
            #pragma unroll
            for (int ss = 0; ss < 8; ++ss) atomicAdd(&gb[ss], w * sem[ss]);
          }
        }
      }
    }
  }
  __syncthreads();
  for (int p = threadIdx.x; p < NVR*8; p += 256) {
    int x = p >> 3, ss = p & 7;
    float acc = 0.0f;
    #pragma unroll
    for (int z = 0; z < NZB; ++z) acc += rintf(g[(x*NZB + z)*8 + ss]);
    float val = fminf(fmaxf(acc / 5.0f, 0.0f), 1.0f);
    proj[(((size_t)b*NC + 4 + half*8 + ss)*NVR + Y)*NVR + x] = val;
  }
}

// ---------------- fused rotate+translate grid_sample + max ----------------
__global__ __launch_bounds__(256) void transform_kernel(
    const float* __restrict__ maps_last, const float* __restrict__ proj,
    const float* __restrict__ params, float* __restrict__ d_out)
{
  int tid = blockIdx.x * 256 + threadIdx.x;
  int b = tid / (NM*NM);
  int rem = tid - b*(NM*NM);
  int h = rem / NM;
  int w = rem - h*NM;

  float ct = params[b*4+0];
  float st = params[b*4+1];
  float tx = params[b*4+2];
  float ty = params[b*4+3];

  const float step = 2.0f/479.0f;
  float gx = -1.0f + (float)w * step;
  float gy = -1.0f + (float)h * step;
  float X2 = ((gx + tx) + 1.0f) * 0.5f * 479.0f;
  float Y2 = ((gy + ty) + 1.0f) * 0.5f * 479.0f;
  float x0 = floorf(X2), y0 = floorf(Y2);
  float wox[2] = {(x0 + 1.0f) - X2, X2 - x0};
  float woy[2] = {(y0 + 1.0f) - Y2, Y2 - y0};

  float twt[16];
  int   toff[16];
  int nz = 0;
  #pragma unroll
  for (int oy = 0; oy < 2; ++oy) {
    #pragma unroll
    for (int ox = 0; ox < 2; ++ox) {
      int kb = (oy*2 + ox)*4;
      float cx = x0 + (float)ox;
      float cy = y0 + (float)oy;
      float wo = wox[ox]*woy[oy];
      bool ov = (cx >= 0.0f) && (cx <= 479.0f) && (cy >= 0.0f) && (cy <= 479.0f);
      if (ov) {
        float gxr = -1.0f + cx * step;
        float gyr = -1.0f + cy * step;
        float xr = gxr*ct - gyr*st;
        float yr = gxr*st + gyr*ct;
        float XS = (xr + 1.0f)*0.5f*479.0f;
        float YS = (yr + 1.0f)*0.5f*479.0f;
        float ix0 = floorf(XS), iy0 = floorf(YS);
        float wix[2] = {(ix0+1.0f)-XS, XS-ix0};
        float wiy[2] = {(iy0+1.0f)-YS, YS-iy0};
        #pragma unroll
        for (int qy = 0; qy < 2; ++qy) {
          #pragma unroll
          for (int qx = 0; qx < 2; ++qx) {
            int k = kb + qy*2 + qx;
            float ux = ix0 + (float)qx;
            float vy = iy0 + (float)qy;
            float wv = 0.0f; int off = 0;
            if (ux >= 0.0f && ux <= 479.0f && vy >= 0.0f && vy <= 479.0f) {
              int U = (int)ux, V = (int)vy;
              if (U >= 190 && U < 290 && V >= 240 && V < 340) {
                off = (V - 240)*NVR + (U - 190);
                wv = wo * (wix[qx]*wiy[qy]);
              }
            }
            twt[k] = wv; toff[k] = off;
            nz += (wv != 0.0f) ? 1 : 0;
          }
        }
      } else {
        #pragma unroll
        for (int k = 0; k < 4; ++k) { twt[kb+k] = 0.0f; toff[kb+k] = 0; }
      }
    }
  }

  const float* pbase = proj + (size_t)b*NC*NVR*NVR;
  size_t base_idx = (size_t)b*NC*NM*NM + (size_t)h*NM + w;
  if (nz > 0) {
    #pragma unroll 1
    for (int c = 0; c < NC; ++c) {
      size_t idx = base_idx + (size_t)c*NM*NM;
      float ml = maps_last[idx];
      float val = 0.0f;
      if (c != 2 && c != 3) {
        const float* pc = pbase + (size_t)c*NVR*NVR;
        #pragma unroll
        for (int k = 0; k < 16; ++k) val += twt[k]*pc[toff[k]];
      }
      d_out[40000 + idx] = fmaxf(ml, val);
    }
  } else {
    #pragma unroll 1
    for (int c = 0; c < NC; ++c) {
      size_t idx = base_idx + (size_t)c*NM*NM;
      d_out[40000 + idx] = fmaxf(maps_last[idx], 0.0f);
    }
  }
}

extern "C" void kernel_launch(void* const* d_in, const int* in_sizes, int n_in,
                              void* d_out, int out_size, void* d_ws, size_t ws_size,
                              hipStream_t stream)
{
  const float* obs        = (const float*)d_in[0];
  const float* pose_obs   = (const float*)d_in[1];
  const float* maps_last  = (const float*)d_in[2];
  const float* poses_last = (const float*)d_in[3];
  float* out = (float*)d_out;

  char* ws = (char*)d_ws;
  int*    hist    = (int*)(ws + WS_HIST);
  int*    starts  = (int*)(ws + WS_STARTS);
  int*    cursors = (int*)(ws + WS_CURS);
  float*  params  = (float*)(ws + WS_PARAMS);
  int*    h2d     = (int*)(ws + WS_H2D);
  int*    s2d     = (int*)(ws + WS_S2D);
  int*    c2d     = (int*)(ws + WS_C2D);
  float4* recs    = (float4*)(ws + WS_RECS);
  float*  proj    = (float*)(ws + WS_PROJ);
  float4* sgeom   = (float4*)(ws + WS_SGEOM);
  float*  semT    = (float*)(ws + WS_SEMT);

  const bool fast = ws_size >= (size_t)WS_FAST_END;

  // zero hist/starts/cursors/params + h2d
  hipMemsetAsync(ws, 0, WS_S2D, stream);

  const float foc = (float)(((double)NW) / 2.0 / tan(79.0 * 0.5 * M_PI / 180.0));

  pose_kernel<<<1, 64, 0, stream>>>(pose_obs, poses_last, out + 40000 + 18432000, params);
  if (fast)
    semt_kernel<<<NB*1200, 256, 0, stream>>>(obs, semT);
  hist_kernel<<<NB*300, 256, 0, stream>>>(obs, hist, h2d, foc, fast ? 1 : 0);
  scan_kernel<<<1, 512, 0, stream>>>(hist, starts, cursors);
  if (fast)
    scan2d_kernel<<<1, 512, 0, stream>>>(h2d, s2d, c2d);
  scatter_kernel<<<NB*300, 256, 0, stream>>>(obs, cursors, c2d, recs, sgeom,
                                             foc, fast ? 1 : 0);
  slab0f_kernel<<<NB*NVR, 256, 0, stream>>>(recs, starts, proj, out);
  if (fast)
    slab1g_kernel<<<NB*NVR, 512, 0, stream>>>(semT, sgeom, s2d, proj);
  else
    slab1_kernel<<<NB*NVR*2, 256, 0, stream>>>(obs, recs, starts, proj);
  transform_kernel<<<(NB*NM*NM)/256, 256, 0, stream>>>(maps_last, proj, params, out);
}

// Round 8
// 683.761 us; speedup vs baseline: 1.6748x; 1.6748x over previous
//
#include <hip/hip_runtime.h>
#include <math.h>

#define NB 4
#define NC 20
#define NH 480
#define NW 640
#define NPIX (NH*NW)      // 307200
#define NM 480
#define NVR 100
#define NNZ 80
#define ZLO 13
#define ZHI 25
#define NZB 12
#define NBINS 101         // y0 bucket 0..100 (100 = dead)
#define SREC_CAP 524288   // band-record capacity (derived ~293K, 1.8x margin)
#define NB2D 40400        // 4 * 101 * 100 (y0,x0) bins
#define NWAVES 6400       // maccum waves (1600 blocks x 4)

// workspace offsets
#define WS_HIST     0
#define WS_STARTS   2048
#define WS_CURS     4096
#define WS_PARAMS   6144
#define WS_H2D      8192                              // 40400 ints -> ends 169792
#define WS_S2D      172032                            // 40401 ints
#define WS_C2D      335872                            // 40400 ints
#define WS_RECS     499712                            // 1,228,800 * 16B
#define WS_PROJ     (WS_RECS + 19660800)              // 20,160,512
#define WS_SGEOM    (WS_PROJ + 3200000)               // 23,360,512
#define WS_M        (WS_SGEOM + (size_t)SREC_CAP*16)  // 31,749,120
#define WS_FAST_END (WS_M + (size_t)NB2D*384*4)       // 93,803,520 (ws >= 114.5MB proven)

// exact replication of the reference f32 op chains
__device__ __forceinline__ float p1_chain(float d) {
  float xy1 = d / 5.0f;
  xy1 = (xy1 - 50.0f) / 100.0f * 2.0f;
  return xy1 * 50.0f + 50.0f;
}
__device__ __forceinline__ void p02_chain(float d, int row, int col, float foc,
                                          float& p0, float& p2) {
  float X = ((float)col - 319.5f) * d / foc;
  float Z = ((float)(479 - row) - 239.5f) * d / foc;
  float xy0 = (X + 250.0f) / 5.0f;
  xy0 = (xy0 - 50.0f) / 100.0f * 2.0f;
  float zz = (Z + 88.0f) / 5.0f;
  zz = (zz - 32.0f) / 80.0f * 2.0f;
  p0 = xy0 * 50.0f + 50.0f;
  p2 = zz * 40.0f + 40.0f;
}
__device__ __forceinline__ bool band_ok(float p0, float p2) {
  return (p0 > 0.0f) && (p0 < 100.0f) &&
         (p2 > (float)(ZLO - 1)) && (p2 < (float)ZHI);
}

// ---------------- pose + affine params ----------------
__global__ __launch_bounds__(64) void pose_kernel(
    const float* __restrict__ pose_obs, const float* __restrict__ poses_last,
    float* __restrict__ out_poses, float* __restrict__ params)
{
  int b = threadIdx.x;
  if (b >= NB) return;
  const float R2D = 57.29577951308232f;
  float plx = poses_last[b*3+0], ply = poses_last[b*3+1], plo = poses_last[b*3+2];
  float dx = pose_obs[b*3+0], dy = pose_obs[b*3+1], dth = pose_obs[b*3+2];
  float r = plo / R2D;
  float sr = sinf(r), cr = cosf(r);
  float yy = ply + dx*sr + dy*cr;
  float xx = plx + dx*cr - dy*sr;
  float oo = plo + dth*R2D;
  oo = fmodf(oo - 180.0f, 360.0f) + 180.0f;
  oo = fmodf(oo + 180.0f, 360.0f) - 180.0f;
  out_poses[b*3+0] = xx;
  out_poses[b*3+1] = yy;
  out_poses[b*3+2] = oo;
  float tx = -((xx*100.0f/5.0f) - 240.0f) / 240.0f;
  float ty = -((yy*100.0f/5.0f) - 240.0f) / 240.0f;
  float th = ((90.0f - oo) * 3.14159274101257324f) / 180.0f;
  params[b*4+0] = cosf(th);
  params[b*4+1] = sinf(th);
  params[b*4+2] = tx;
  params[b*4+3] = ty;
}

// ---------------- histogram: y-buckets (LDS) + (y,x) 2D bins (global atomics) ----------------
__global__ __launch_bounds__(256) void hist_kernel(
    const float* __restrict__ obs, int* __restrict__ hist, int* __restrict__ h2d,
    float foc, int do2d)
{
  int b = blockIdx.x / 300, blk = blockIdx.x % 300;
  __shared__ int lh[NBINS];
  for (int i = threadIdx.x; i < NBINS; i += 256) lh[i] = 0;
  __syncthreads();
  int pix0 = (blk*256 + threadIdx.x)*4;
  int row = pix0 / NW;
  int c0 = pix0 - row*NW;
  const float4* dp = (const float4*)(obs + ((size_t)b*NC + 3)*NPIX);
  float4 dv = dp[blk*256 + threadIdx.x];
  float dvv[4] = {dv.x, dv.y, dv.z, dv.w};
  #pragma unroll
  for (int k = 0; k < 4; ++k) {
    float p1 = p1_chain(dvv[k]);
    int y0 = (int)floorf(p1);
    y0 = min(max(y0, 0), 100);
    atomicAdd(&lh[y0], 1);
    float p0, p2;
    p02_chain(dvv[k], row, c0 + k, foc, p0, p2);
    if (do2d && band_ok(p0, p2)) {
      int x0 = (int)floorf(p0);            // band -> 0..99
      atomicAdd(&h2d[(b*NBINS + y0)*100 + x0], 1);
    }
  }
  __syncthreads();
  for (int i = threadIdx.x; i < NBINS; i += 256)
    if (lh[i]) atomicAdd(&hist[b*NBINS + i], lh[i]);
}

// ---------------- exclusive scan of y-bins ----------------
__global__ __launch_bounds__(512) void scan_kernel(
    const int* __restrict__ hist, int* __restrict__ starts, int* __restrict__ cursors)
{
  __shared__ int lh[NB*NBINS];
  __shared__ int ls[NB*NBINS + 1];
  for (int i = threadIdx.x; i < NB*NBINS; i += 512) lh[i] = hist[i];
  __syncthreads();
  if (threadIdx.x == 0) {
    int s = 0;
    for (int i = 0; i < NB*NBINS; ++i) { ls[i] = s; s += lh[i]; }
    ls[NB*NBINS] = s;
  }
  __syncthreads();
  for (int i = threadIdx.x; i < NB*NBINS + 1; i += 512) {
    starts[i] = ls[i];
    if (i < NB*NBINS) cursors[i] = ls[i];
  }
}

// ---------------- exclusive scan of 40400 2D bins (LDS-tiled, coalesced) ----------------
__global__ __launch_bounds__(512) void scan2d_kernel(
    const int* __restrict__ h2d, int* __restrict__ s2d, int* __restrict__ c2d)
{
  __shared__ int tile[10100];
  __shared__ int thsum[512];
  __shared__ int run_s;
  int t = threadIdx.x;
  if (t == 0) run_s = 0;
  __syncthreads();
  for (int T = 0; T < 4; ++T) {
    int base = T*10100;
    for (int i = t; i < 10100; i += 512) tile[i] = h2d[base + i];
    __syncthreads();
    int c0 = t*20, c1 = min(c0 + 20, 10100);
    int s = 0;
    for (int i = c0; i < c1; ++i) s += tile[i];
    thsum[t] = s;
    __syncthreads();
    if (t == 0) {
      int r = run_s;
      for (int k = 0; k < 512; ++k) { int v = thsum[k]; thsum[k] = r; r += v; }
      run_s = r;
    }
    __syncthreads();
    int r = thsum[t];
    for (int i = c0; i < c1; ++i) { int v = tile[i]; tile[i] = r; r += v; }
    __syncthreads();
    for (int i = t; i < 10100; i += 512) {
      int v = tile[i];
      s2d[base + i] = v;
      c2d[base + i] = v;
    }
    __syncthreads();
  }
  if (t == 0) s2d[NB2D] = run_s;
}

// ---------------- scatter pixel records into buckets (R7-verified) ----------------
__global__ __launch_bounds__(256) void scatter_kernel(
    const float* __restrict__ obs, int* __restrict__ cursors, int* __restrict__ c2d,
    float4* __restrict__ recs, float4* __restrict__ sgeom,
    float foc, int do_band)
{
  int b = blockIdx.x / 300, blk = blockIdx.x % 300;
  __shared__ int lh[NBINS], lbase[NBINS], loff[NBINS];
  for (int i = threadIdx.x; i < NBINS; i += 256) { lh[i] = 0; loff[i] = 0; }
  __syncthreads();
  int pix0 = (blk*256 + threadIdx.x)*4;
  int row = pix0 / NW;
  int c0 = pix0 - row*NW;   // 4-pixel group never crosses a row (640 % 4 == 0)
  const float4* dp = (const float4*)(obs + ((size_t)b*NC + 3)*NPIX);
  float4 dv = dp[blk*256 + threadIdx.x];
  float dvv[4] = {dv.x, dv.y, dv.z, dv.w};
  float rp0[4], rp1[4], rp2[4]; int rbin[4];
  #pragma unroll
  for (int k = 0; k < 4; ++k) {
    float p1 = p1_chain(dvv[k]);
    float p0, p2;
    p02_chain(dvv[k], row, c0 + k, foc, p0, p2);
    rp0[k] = p0; rp1[k] = p1; rp2[k] = p2;
    int y0 = (int)floorf(p1); y0 = min(max(y0, 0), 100);
    rbin[k] = y0;
    atomicAdd(&lh[y0], 1);
  }
  __syncthreads();
  for (int i = threadIdx.x; i < NBINS; i += 256)
    if (lh[i] > 0) lbase[i] = atomicAdd(&cursors[b*NBINS + i], lh[i]);
  __syncthreads();
  #pragma unroll
  for (int k = 0; k < 4; ++k) {
    int idx = atomicAdd(&loff[rbin[k]], 1);
    recs[lbase[rbin[k]] + idx] =
        make_float4(rp0[k], rp1[k], rp2[k], __int_as_float(pix0 + k));
    if (do_band && band_ok(rp0[k], rp2[k])) {
      int x0 = (int)floorf(rp0[k]);
      int bin = (b*NBINS + rbin[k])*100 + x0;
      int j = atomicAdd(&c2d[bin], 1);
      if (j < SREC_CAP)
        sgeom[j] = make_float4(rp0[k], rp1[k], rp2[k], __int_as_float(pix0 + k));
    }
  }
}

// ---------------- ch0 slab, unroll-4 prefetch (unchanged, verified) ----------------
__global__ __launch_bounds__(256) void slab0f_kernel(
    const float4* __restrict__ recs, const int* __restrict__ starts,
    float* __restrict__ proj, float* __restrict__ out_fp)
{
  int b = blockIdx.x / NVR, Y = blockIdx.x % NVR;
  __shared__ float g[NVR*81];
  for (int i = threadIdx.x; i < NVR*81; i += 256) g[i] = 0.0f;
  __syncthreads();
  if (Y > 0) {
    int lo = starts[b*NBINS + Y - 1];
    int hi = starts[b*NBINS + Y + 1];
    float Yf = (float)Y;
    for (int i = lo + threadIdx.x; i < hi; i += 1024) {
      float4 rr[4];
      #pragma unroll
      for (int k = 0; k < 4; ++k) {
        int j = i + k*256;
        rr[k] = (j < hi) ? recs[j] : make_float4(0.0f, -1.0e9f, 0.0f, 0.0f);
      }
      #pragma unroll
      for (int k = 0; k < 4; ++k) {
        float4 r = rr[k];
        float wy = 1.0f - fabsf(r.y - Yf);
        if (wy <= 0.0f) continue;
        float p0 = r.x, p2 = r.z;
        float fl0 = floorf(p0), fl2 = floorf(p2);
        #pragma unroll
        for (int xo = 0; xo < 2; ++xo) {
          float px = fl0 + (float)xo;
          if (!(px > 0.0f && px < 100.0f)) continue;
          float wxy = (1.0f - fabsf(p0 - px)) * wy;
          if (wxy <= 0.0f) continue;
          int ix = (int)px;
          #pragma unroll
          for (int zo = 0; zo < 2; ++zo) {
            float pz = fl2 + (float)zo;
            if (!(pz > 0.0f && pz < 80.0f)) continue;
            float w = wxy * (1.0f - fabsf(p2 - pz));
            if (w > 0.0f) atomicAdd(&g[ix*81 + (int)pz], w);
          }
        }
      }
    }
  }
  __syncthreads();
  if (threadIdx.x < NVR) {
    int x = threadIdx.x;
    float s_all = 0.0f, s_ag = 0.0f;
    for (int z = 0; z < NNZ; ++z) {
      float v = rintf(g[x*81 + z]);
      s_all += v;
      if (z >= ZLO && z < ZHI) s_ag += v;
    }
    float fp_map = fminf(fmaxf(s_ag, 0.0f), 1.0f);
    float fp_exp = fminf(fmaxf(s_all, 0.0f), 1.0f);
    size_t pb = (((size_t)b*NC + 0)*NVR + Y)*NVR + x;
    proj[pb] = fp_map;
    proj[pb + NVR*NVR] = fp_exp;
    proj[pb + 2*NVR*NVR] = 0.0f;
    proj[pb + 3*NVR*NVR] = 0.0f;
    out_fp[(size_t)b*NVR*NVR + Y*NVR + x] = fp_map;
  }
}

// ---------------- bin-moment accumulator: one wave per bin, NO atomics ----------------
// lane = s(8) + 8*dydx(4) + 32*rslot(2). Per record-pair: weights + 12 predicated
// register FMAs. M[bin][z:12][dydx:4][s:8], written coalesced (lanes 0..31 per z).
__global__ __launch_bounds__(256) void maccum_kernel(
    const float* __restrict__ obs, const float4* __restrict__ sgeom,
    const int* __restrict__ s2d, float* __restrict__ M, int h)
{
  int lane = threadIdx.x & 63;
  int wid = (blockIdx.x << 2) | (threadIdx.x >> 6);
  int s = lane & 7;
  int dydx = (lane >> 3) & 3;
  int dxo = dydx & 1, dyo = dydx >> 1;
  int r = lane >> 5;
  for (int bin = wid; bin < NB2D; bin += NWAVES) {
    int bb = bin / 10100;
    int rem = bin - bb*10100;
    int y0 = rem / 100;
    int x0 = rem - y0*100;
    const float* sbase = obs + ((size_t)bb*NC + 4 + h*8 + s)*NPIX;
    float fy = (float)(y0 + dyo);
    float fx = (float)(x0 + dxo);
    int lo = s2d[bin], hi = s2d[bin + 1];
    float acc[NZB];
    #pragma unroll
    for (int j = 0; j < NZB; ++j) acc[j] = 0.0f;
    for (int base2 = lo; base2 < hi; base2 += 2) {
      int idx = base2 + r;
      float4 gq = (idx < hi) ? sgeom[idx]
                             : make_float4(0.0f, -1.0e9f, 0.0f, __int_as_float(0));
      int pid = __float_as_int(gq.w);
      float sem = sbase[pid];
      float wy = fmaxf(1.0f - fabsf(gq.y - fy), 0.0f);
      float wx = fmaxf(1.0f - fabsf(gq.x - fx), 0.0f);
      float ws = wy * wx * sem;
      float tz = gq.z - (float)ZLO;
      #pragma unroll
      for (int j = 0; j < NZB; ++j)
        acc[j] += fmaxf(1.0f - fabsf(tz - (float)j), 0.0f) * ws;
    }
    float* Mb = M + (size_t)bin*384;
    #pragma unroll
    for (int j = 0; j < NZB; ++j) {
      float v = acc[j] + __shfl_xor(acc[j], 32);
      if (r == 0) Mb[j*32 + dydx*8 + s] = v;
    }
  }
}

// ---------------- cell assembly: cell = sum of 4 bins' moments ----------------
__global__ __launch_bounds__(256) void semcell_kernel(
    const float* __restrict__ M, float* __restrict__ proj, int h)
{
  int b = blockIdx.x / NVR, Y = blockIdx.x % NVR;
  for (int p = threadIdx.x; p < NVR*8; p += 256) {
    int x = p >> 3, s = p & 7;
    float val = 0.0f;
    if (Y > 0 && x > 0) {
      int binA = (b*NBINS + Y)*100 + x;        // (y0=Y,   x0=x)   dydx=0
      const float* A = M + (size_t)binA*384 + s;
      const float* Bp = M + (size_t)(binA - 1)*384 + 8 + s;      // (Y,   x-1) dx=1
      const float* Cp = M + (size_t)(binA - 100)*384 + 16 + s;   // (Y-1, x)   dy=1
      const float* Dp = M + (size_t)(binA - 101)*384 + 24 + s;   // (Y-1, x-1) dydx=3
      float acc = 0.0f;
      #pragma unroll
      for (int j = 0; j < NZB; ++j)
        acc += rintf(A[j*32] + Bp[j*32] + Cp[j*32] + Dp[j*32]);
      val = fminf(fmaxf(acc / 5.0f, 0.0f), 1.0f);
    }
    proj[(((size_t)b*NC + 4 + h*8 + s)*NVR + Y)*NVR + x] = val;
  }
}

// ---------------- fallback sem slab (ws too small; R0-proven) ----------------
__global__ __launch_bounds__(256) void slab1_kernel(
    const float* __restrict__ obs, const float4* __restrict__ recs,
    const int* __restrict__ starts, float* __restrict__ proj)
{
  int half = blockIdx.x & 1;
  int t = blockIdx.x >> 1;
  int b = t / NVR, Y = t % NVR;
  __shared__ float g[NVR*NZB*8];
  for (int i = threadIdx.x; i < NVR*NZB*8; i += 256) g[i] = 0.0f;
  __syncthreads();
  if (Y > 0) {
    int lo = starts[b*NBINS + Y - 1];
    int hi = starts[b*NBINS + Y + 1];
    float Yf = (float)Y;
    const float* sbase = obs + ((size_t)b*NC + 4 + half*8)*NPIX;
    for (int i = lo + threadIdx.x; i < hi; i += 256) {
      float4 r = recs[i];
      float wy = 1.0f - fabsf(r.y - Yf);
      if (wy <= 0.0f) continue;
      float p2 = r.z;
      float fl2 = floorf(p2);
      float wz[2]; int iz[2]; bool any = false;
      #pragma unroll
      for (int zo = 0; zo < 2; ++zo) {
        float pz = fl2 + (float)zo;
        bool v = (pz >= (float)ZLO) && (pz < (float)ZHI);
        float w = v ? (1.0f - fabsf(p2 - pz)) : 0.0f;
        wz[zo] = w; iz[zo] = v ? ((int)pz - ZLO) : 0;
        any = any || (w > 0.0f);
      }
      if (!any) continue;
      float p0 = r.x;
      float fl0 = floorf(p0);
      int pid = __float_as_int(r.w);
      float sem[8];
      #pragma unroll
      for (int ss = 0; ss < 8; ++ss) sem[ss] = sbase[(size_t)ss*NPIX + pid];
      #pragma unroll
      for (int xo = 0; xo < 2; ++xo) {
        float px = fl0 + (float)xo;
        if (!(px > 0.0f && px < 100.0f)) continue;
        float wxy = (1.0f - fabsf(p0 - px)) * wy;
        if (wxy <= 0.0f) continue;
        int ix = (int)px;
        #pragma unroll
        for (int zo = 0; zo < 2; ++zo) {
          float w = wxy * wz[zo];
          if (w > 0.0f) {
            float* gb = &g[(ix*NZB + iz[zo])*8];
            #pragma unroll
            for (int ss = 0; ss < 8; ++ss) atomicAdd(&gb[ss], w * sem[ss]);
          }
        }
      }
    }
  }
  __syncthreads();
  for (int p = threadIdx.x; p < NVR*8; p += 256) {
    int x = p >> 3, ss = p & 7;
    float acc = 0.0f;
    #pragma unroll
    for (int z = 0; z < NZB; ++z) acc += rintf(g[(x*NZB + z)*8 + ss]);
    float val = fminf(fmaxf(acc / 5.0f, 0.0f), 1.0f);
    proj[(((size_t)b*NC + 4 + half*8 + ss)*NVR + Y)*NVR + x] = val;
  }
}

// ---------------- fused rotate+translate grid_sample + max ----------------
__global__ __launch_bounds__(256) void transform_kernel(
    const float* __restrict__ maps_last, const float* __restrict__ proj,
    const float* __restrict__ params, float* __restrict__ d_out)
{
  int tid = blockIdx.x * 256 + threadIdx.x;
  int b = tid / (NM*NM);
  int rem = tid - b*(NM*NM);
  int h = rem / NM;
  int w = rem - h*NM;

  float ct = params[b*4+0];
  float st = params[b*4+1];
  float tx = params[b*4+2];
  float ty = params[b*4+3];

  const float step = 2.0f/479.0f;
  float gx = -1.0f + (float)w * step;
  float gy = -1.0f + (float)h * step;
  float X2 = ((gx + tx) + 1.0f) * 0.5f * 479.0f;
  float Y2 = ((gy + ty) + 1.0f) * 0.5f * 479.0f;
  float x0 = floorf(X2), y0 = floorf(Y2);
  float wox[2] = {(x0 + 1.0f) - X2, X2 - x0};
  float woy[2] = {(y0 + 1.0f) - Y2, Y2 - y0};

  float twt[16];
  int   toff[16];
  int nz = 0;
  #pragma unroll
  for (int oy = 0; oy < 2; ++oy) {
    #pragma unroll
    for (int ox = 0; ox < 2; ++ox) {
      int kb = (oy*2 + ox)*4;
      float cx = x0 + (float)ox;
      float cy = y0 + (float)oy;
      float wo = wox[ox]*woy[oy];
      bool ov = (cx >= 0.0f) && (cx <= 479.0f) && (cy >= 0.0f) && (cy <= 479.0f);
      if (ov) {
        float gxr = -1.0f + cx * step;
        float gyr = -1.0f + cy * step;
        float xr = gxr*ct - gyr*st;
        float yr = gxr*st + gyr*ct;
        float XS = (xr + 1.0f)*0.5f*479.0f;
        float YS = (yr + 1.0f)*0.5f*479.0f;
        float ix0 = floorf(XS), iy0 = floorf(YS);
        float wix[2] = {(ix0+1.0f)-XS, XS-ix0};
        float wiy[2] = {(iy0+1.0f)-YS, YS-iy0};
        #pragma unroll
        for (int qy = 0; qy < 2; ++qy) {
          #pragma unroll
          for (int qx = 0; qx < 2; ++qx) {
            int k = kb + qy*2 + qx;
            float ux = ix0 + (float)qx;
            float vy = iy0 + (float)qy;
            float wv = 0.0f; int off = 0;
            if (ux >= 0.0f && ux <= 479.0f && vy >= 0.0f && vy <= 479.0f) {
              int U = (int)ux, V = (int)vy;
              if (U >= 190 && U < 290 && V >= 240 && V < 340) {
                off = (V - 240)*NVR + (U - 190);
                wv = wo * (wix[qx]*wiy[qy]);
              }
            }
            twt[k] = wv; toff[k] = off;
            nz += (wv != 0.0f) ? 1 : 0;
          }
        }
      } else {
        #pragma unroll
        for (int k = 0; k < 4; ++k) { twt[kb+k] = 0.0f; toff[kb+k] = 0; }
      }
    }
  }

  const float* pbase = proj + (size_t)b*NC*NVR*NVR;
  size_t base_idx = (size_t)b*NC*NM*NM + (size_t)h*NM + w;
  if (nz > 0) {
    #pragma unroll 1
    for (int c = 0; c < NC; ++c) {
      size_t idx = base_idx + (size_t)c*NM*NM;
      float ml = maps_last[idx];
      float val = 0.0f;
      if (c != 2 && c != 3) {
        const float* pc = pbase + (size_t)c*NVR*NVR;
        #pragma unroll
        for (int k = 0; k < 16; ++k) val += twt[k]*pc[toff[k]];
      }
      d_out[40000 + idx] = fmaxf(ml, val);
    }
  } else {
    #pragma unroll 1
    for (int c = 0; c < NC; ++c) {
      size_t idx = base_idx + (size_t)c*NM*NM;
      d_out[40000 + idx] = fmaxf(maps_last[idx], 0.0f);
    }
  }
}

extern "C" void kernel_launch(void* const* d_in, const int* in_sizes, int n_in,
                              void* d_out, int out_size, void* d_ws, size_t ws_size,
                              hipStream_t stream)
{
  const float* obs        = (const float*)d_in[0];
  const float* pose_obs   = (const float*)d_in[1];
  const float* maps_last  = (const float*)d_in[2];
  const float* poses_last = (const float*)d_in[3];
  float* out = (float*)d_out;

  char* ws = (char*)d_ws;
  int*    hist    = (int*)(ws + WS_HIST);
  int*    starts  = (int*)(ws + WS_STARTS);
  int*    cursors = (int*)(ws + WS_CURS);
  float*  params  = (float*)(ws + WS_PARAMS);
  int*    h2d     = (int*)(ws + WS_H2D);
  int*    s2d     = (int*)(ws + WS_S2D);
  int*    c2d     = (int*)(ws + WS_C2D);
  float4* recs    = (float4*)(ws + WS_RECS);
  float*  proj    = (float*)(ws + WS_PROJ);
  float4* sgeom   = (float4*)(ws + WS_SGEOM);
  float*  M       = (float*)(ws + WS_M);

  const bool fast = ws_size >= (size_t)WS_FAST_END;

  // zero hist/starts/cursors/params + h2d
  hipMemsetAsync(ws, 0, WS_S2D, stream);

  const float foc = (float)(((double)NW) / 2.0 / tan(79.0 * 0.5 * M_PI / 180.0));

  pose_kernel<<<1, 64, 0, stream>>>(pose_obs, poses_last, out + 40000 + 18432000, params);
  hist_kernel<<<NB*300, 256, 0, stream>>>(obs, hist, h2d, foc, fast ? 1 : 0);
  scan_kernel<<<1, 512, 0, stream>>>(hist, starts, cursors);
  if (fast)
    scan2d_kernel<<<1, 512, 0, stream>>>(h2d, s2d, c2d);
  scatter_kernel<<<NB*300, 256, 0, stream>>>(obs, cursors, c2d, recs, sgeom,
                                             foc, fast ? 1 : 0);
  slab0f_kernel<<<NB*NVR, 256, 0, stream>>>(recs, starts, proj, out);
  if (fast) {
    maccum_kernel<<<NWAVES/4, 256, 0, stream>>>(obs, sgeom, s2d, M, 0);
    semcell_kernel<<<NB*NVR, 256, 0, stream>>>(M, proj, 0);
    maccum_kernel<<<NWAVES/4, 256, 0, stream>>>(obs, sgeom, s2d, M, 1);
    semcell_kernel<<<NB*NVR, 256, 0, stream>>>(M, proj, 1);
  } else {
    slab1_kernel<<<NB*NVR*2, 256, 0, stream>>>(obs, recs, starts, proj);
  }
  transform_kernel<<<(NB*NM*NM)/256, 256, 0, stream>>>(maps_last, proj, params, out);
}